// Round 8
// baseline (2335.109 us; speedup 1.0000x reference)
//
#include <hip/hip_runtime.h>
#include <string.h>

#define B 4
#define N 16384
#define D 256
#define K 512
#define ITERS 10

typedef short short8 __attribute__((ext_vector_type(8)));
typedef float float4v __attribute__((ext_vector_type(4)));

// ---------------- host MT19937 exactly matching CPython random.seed(42); random.sample(range(16384), 512)
static void host_sample_inds(int* out) {
    static unsigned int mt[624];
    mt[0] = 19650218u;
    for (int i = 1; i < 624; i++)
        mt[i] = 1812433253u * (mt[i - 1] ^ (mt[i - 1] >> 30)) + (unsigned)i;
    {
        int i = 1, j = 0;
        for (int kk = 624; kk; kk--) {
            mt[i] = (mt[i] ^ ((mt[i - 1] ^ (mt[i - 1] >> 30)) * 1664525u)) + 42u + (unsigned)j;
            i++; j++;
            if (i >= 624) { mt[0] = mt[623]; i = 1; }
            if (j >= 1) j = 0;
        }
        for (int kk = 623; kk; kk--) {
            mt[i] = (mt[i] ^ ((mt[i - 1] ^ (mt[i - 1] >> 30)) * 1566083941u)) - (unsigned)i;
            i++;
            if (i >= 624) { mt[0] = mt[623]; i = 1; }
        }
        mt[0] = 0x80000000u;
    }
    static unsigned char seen[N];
    memset(seen, 0, sizeof(seen));
    int mti = 624;
    int got = 0;
    while (got < K) {
        if (mti >= 624) {
            for (int kk = 0; kk < 624; kk++) {
                unsigned int yy = (mt[kk] & 0x80000000u) | (mt[(kk + 1) % 624] & 0x7fffffffu);
                mt[kk] = mt[(kk + 397) % 624] ^ (yy >> 1) ^ ((yy & 1u) ? 0x9908b0dfu : 0u);
            }
            mti = 0;
        }
        unsigned int y = mt[mti++];
        y ^= y >> 11; y ^= (y << 7) & 0x9d2c5680u; y ^= (y << 15) & 0xefc60000u; y ^= y >> 18;
        unsigned int r = y >> 17;
        if (r >= (unsigned)N) continue;
        if (seen[r]) continue;
        seen[r] = 1;
        out[got++] = (int)r;
    }
}

__device__ inline void gload_lds16(const void* g, void* l) {
    __builtin_amdgcn_global_load_lds((const __attribute__((address_space(1))) void*)g,
                                     (__attribute__((address_space(3))) void*)l, 16, 0, 0);
}

__device__ inline unsigned bf16_rne(float f) {
    unsigned u = __float_as_uint(f);
    return (u + 0x7fffu + ((u >> 16) & 1u)) >> 16;
}

// =================== prep ===================

__global__ void k_gather_v0(const float* __restrict__ x, const int* __restrict__ inds,
                            float* __restrict__ v) {
    int bk = blockIdx.x; int b = bk / K, k = bk % K;
    int n = inds[k];
    const float4* src = (const float4*)(x + ((size_t)b * N + n) * D);
    float4* dst = (float4*)(v + ((size_t)b * K + k) * D);
    dst[threadIdx.x] = src[threadIdx.x];
}

__global__ void k_totsum(const float* __restrict__ x, float* __restrict__ totsum) {
    int b = blockIdx.y;
    int n0 = blockIdx.x * (N / 64);
    int t = threadIdx.x;
    const float* xb = x + (size_t)b * N * D;
    float s = 0.f;
    for (int n = n0; n < n0 + N / 64; n++) s += xb[(size_t)n * D + t];
    atomicAdd(&totsum[b * D + t], s);
}

// fused: rownorm + bf16 split + residual norm + lo norm. wave per row.
__global__ void k_prep(const float* __restrict__ src, unsigned short* __restrict__ cat,
                       float* __restrict__ sq, float* __restrict__ resn,
                       float* __restrict__ lon) {
    int wave = threadIdx.x >> 6, lane = threadIdx.x & 63;
    int row = blockIdx.x * 4 + wave;
    float4 f = ((const float4*)(src + (size_t)row * D))[lane];
    float comp[4] = {f.x, f.y, f.z, f.w};
    unsigned short h[4], l[4];
    float r2 = 0.f, l2 = 0.f, n2 = 0.f;
    #pragma unroll
    for (int j = 0; j < 4; j++) {
        n2 += comp[j] * comp[j];
        unsigned hi = bf16_rne(comp[j]);
        float hif = __uint_as_float(hi << 16);
        float r = comp[j] - hif;            // exact in fp32
        unsigned lo = bf16_rne(r);
        float lof = __uint_as_float(lo << 16);
        float res = r - lof;                // dropped residual
        r2 += res * res;
        l2 += lof * lof;
        h[j] = (unsigned short)hi; l[j] = (unsigned short)lo;
    }
    unsigned short* orow = cat + (size_t)row * 512;
    *(ushort4*)&orow[lane * 4] = make_ushort4(h[0], h[1], h[2], h[3]);
    *(ushort4*)&orow[256 + lane * 4] = make_ushort4(l[0], l[1], l[2], l[3]);
    #pragma unroll
    for (int off = 32; off; off >>= 1) {
        r2 += __shfl_xor(r2, off);
        l2 += __shfl_xor(l2, off);
        n2 += __shfl_xor(n2, off);
    }
    if (lane == 0) { sq[row] = n2; resn[row] = sqrtf(r2); lon[row] = sqrtf(l2); }
}

// per-batch maxes: ||v||, ||v residual||, ||v lo||
__global__ void k_errmax(const float* __restrict__ v2, const float* __restrict__ vres,
                         const float* __restrict__ vlo,
                         float* __restrict__ vmaxs, float* __restrict__ vresmaxs,
                         float* __restrict__ vlomaxs) {
    __shared__ float s1[256], s2[256], s3[256];
    int b = blockIdx.x, t = threadIdx.x;
    s1[t] = fmaxf(sqrtf(v2[b * K + t]), sqrtf(v2[b * K + 256 + t]));
    s2[t] = fmaxf(vres[b * K + t], vres[b * K + 256 + t]);
    s3[t] = fmaxf(vlo[b * K + t], vlo[b * K + 256 + t]);
    __syncthreads();
    for (int s = 128; s; s >>= 1) {
        if (t < s) {
            s1[t] = fmaxf(s1[t], s1[t + s]);
            s2[t] = fmaxf(s2[t], s2[t + s]);
            s3[t] = fmaxf(s3[t], s3[t + s]);
        }
        __syncthreads();
    }
    if (t == 0) { vmaxs[b] = s1[0]; vresmaxs[b] = s2[0]; vlomaxs[b] = s3[0]; }
}

__global__ void k_transpose(const float* __restrict__ v, float* __restrict__ vT) {
    int idx = blockIdx.x * 256 + threadIdx.x;   // B*K*D
    int d = idx & 255, c = (idx >> 8) & 511, b = idx >> 17;
    vT[((size_t)b * D + d) * K + c] = v[idx];
}

// =================== fused MFMA GEMM + per-block top-2 ===================
// 12 kt-steps (xh*vh, xh*vl, xl*vh; xl*vl covered by rigorous flag bound — r7-validated).
// A: global_load_lds + XOR swizzle (r4/r6-validated). B: direct global->VGPR fragment
// loads (vcat is 4 MB, L2-resident); issued before the barrier so the barrier's vmcnt(0)
// drain covers them at no extra stall. LDS traffic halves vs r6 (B never touches LDS).
__global__ __launch_bounds__(256) void k_gemm_assign(
    const unsigned short* __restrict__ xcat, const unsigned short* __restrict__ vcat,
    const float* __restrict__ x2, const float* __restrict__ v2,
    float2* __restrict__ pvals, int2* __restrict__ pinds) {
    __shared__ __align__(16) unsigned short As[128 * 64];   // 16 KB
    __shared__ float x2s[128], v2s[128];
    __shared__ float candv[128][2][2];
    __shared__ int candi[128][2][2];
    int b = blockIdx.z, ch = blockIdx.y;
    int n0 = blockIdx.x * 128;
    int tid = threadIdx.x;
    int wv = tid >> 6, lane = tid & 63;
    int wr = wv >> 1, wc = wv & 1;
    int quad = lane >> 4, l16 = lane & 15;
    const unsigned short* xb = xcat + ((size_t)b * N + n0) * 512;
    const unsigned short* vb = vcat + ((size_t)b * K + ch * 128) * 512;

    if (tid < 128) {
        x2s[tid] = x2[b * N + n0 + tid];
        v2s[tid] = v2[b * K + ch * 128 + tid];
    }

    // A staging meta (r4-validated swizzle): fetch global chunk c into lds slot l
    int srow[4], schunk[4];
    #pragma unroll
    for (int i = 0; i < 4; i++) {
        int l = i * 256 + wv * 64 + lane;
        srow[i] = l >> 3;
        schunk[i] = (l & 7) ^ ((l >> 3) & 7);
    }
    // B fragment rows for this lane (r4-validated fragment mapping)
    int rB[4];
    #pragma unroll
    for (int f = 0; f < 4; f++) rB[f] = wc * 64 + f * 16 + l16;

    float4v acc[4][4];
    #pragma unroll
    for (int i = 0; i < 4; i++)
        #pragma unroll
        for (int j = 0; j < 4; j++) acc[i][j] = (float4v){0.f, 0.f, 0.f, 0.f};

    for (int kt = 0; kt < 12; kt++) {
        int k4 = (kt & 3) * 64;
        int kcolA = (kt < 8) ? k4 : 256 + k4;                    // xh,xh,xl
        int kcolB = (kt < 4) ? k4 : ((kt < 8) ? 256 + k4 : k4);  // vh,vl,vh
        __syncthreads();                       // previous tile fully consumed
        #pragma unroll
        for (int i = 0; i < 4; i++)
            gload_lds16(xb + (size_t)srow[i] * 512 + kcolA + schunk[i] * 8,
                        (void*)&As[(size_t)(i * 256 + wv * 64) * 8]);
        // B fragments straight to registers (drained by the barrier below)
        short8 bfr[2][4];
        #pragma unroll
        for (int ks = 0; ks < 2; ks++)
            #pragma unroll
            for (int f = 0; f < 4; f++)
                bfr[ks][f] = *(const short8*)(vb + (size_t)rB[f] * 512 + kcolB
                                              + (ks * 4 + quad) * 8);
        __syncthreads();                       // vmcnt(0) drain: A in LDS, B in regs
        #pragma unroll
        for (int ks = 0; ks < 2; ks++) {
            short8 af[4];
            int ccr = ks * 4 + quad;
            #pragma unroll
            for (int f = 0; f < 4; f++) {
                int rA = wr * 64 + f * 16 + l16;
                af[f] = *(const short8*)&As[(rA * 8 + (ccr ^ (rA & 7))) * 8];
            }
            #pragma unroll
            for (int fi = 0; fi < 4; fi++)
                #pragma unroll
                for (int fj = 0; fj < 4; fj++)
                    acc[fi][fj] = __builtin_amdgcn_mfma_f32_16x16x32_bf16(
                        af[fi], bfr[ks][fj], acc[fi][fj], 0, 0, 0);
        }
    }

    // epilogue: per-row top-2 over this block's 128 centers (r6-validated verbatim)
    #pragma unroll
    for (int fi = 0; fi < 4; fi++) {
        #pragma unroll
        for (int r = 0; r < 4; r++) {
            int lrow = wr * 64 + fi * 16 + quad * 4 + r;
            float x2v = x2s[lrow];
            float bv1 = 3.4e38f, bv2 = 3.4e38f; int bi1 = 0x7fffffff, bi2 = 0x7fffffff;
            #pragma unroll
            for (int fj = 0; fj < 4; fj++) {
                int lcol = wc * 64 + fj * 16 + l16;
                float dist = fmaxf((x2v - 2.0f * acc[fi][fj][r]) + v2s[lcol], 0.0f);
                int cg = ch * 128 + lcol;
                if (dist < bv1 || (dist == bv1 && cg < bi1)) {
                    bv2 = bv1; bi2 = bi1; bv1 = dist; bi1 = cg;
                } else if (dist < bv2 || (dist == bv2 && cg < bi2)) {
                    bv2 = dist; bi2 = cg;
                }
            }
            #pragma unroll
            for (int off = 1; off < 16; off <<= 1) {
                float ov1 = __shfl_xor(bv1, off); int oi1 = __shfl_xor(bi1, off);
                float ov2 = __shfl_xor(bv2, off); int oi2 = __shfl_xor(bi2, off);
                if (ov1 < bv1 || (ov1 == bv1 && oi1 < bi1)) {
                    float nv2; int ni2;
                    if (bv1 < ov2 || (bv1 == ov2 && bi1 < oi2)) { nv2 = bv1; ni2 = bi1; }
                    else { nv2 = ov2; ni2 = oi2; }
                    bv1 = ov1; bi1 = oi1; bv2 = nv2; bi2 = ni2;
                } else if (ov1 < bv2 || (ov1 == bv2 && oi1 < bi2)) {
                    bv2 = ov1; bi2 = oi1;
                }
            }
            if (l16 == 0) {
                candv[lrow][wc][0] = bv1; candv[lrow][wc][1] = bv2;
                candi[lrow][wc][0] = bi1; candi[lrow][wc][1] = bi2;
            }
        }
    }
    __syncthreads();
    if (tid < 128) {
        float a1 = candv[tid][0][0], a2 = candv[tid][0][1];
        int   j1 = candi[tid][0][0], j2 = candi[tid][0][1];
        float o1 = candv[tid][1][0], o2 = candv[tid][1][1];
        int   p1 = candi[tid][1][0], p2 = candi[tid][1][1];
        float bv1, bv2; int bi1, bi2;
        if (o1 < a1 || (o1 == a1 && p1 < j1)) {
            bv1 = o1; bi1 = p1;
            if (a1 < o2 || (a1 == o2 && j1 < p2)) { bv2 = a1; bi2 = j1; }
            else { bv2 = o2; bi2 = p2; }
        } else {
            bv1 = a1; bi1 = j1;
            if (o1 < a2 || (o1 == a2 && p1 < j2)) { bv2 = o1; bi2 = p1; }
            else { bv2 = a2; bi2 = j2; }
        }
        size_t p = (size_t)(b * N + n0 + tid);
        pvals[p * 4 + ch] = make_float2(bv1, bv2);
        pinds[p * 4 + ch] = make_int2(bi1, bi2);
    }
}

// merge 4 chunk top-2s -> assign; flag points whose margin < rigorous error bound
__global__ void k_reduce2(const float2* __restrict__ pvals, const int2* __restrict__ pinds,
                          const float* __restrict__ x2, const float* __restrict__ xres,
                          const float* __restrict__ xlo,
                          const float* __restrict__ vmaxs, const float* __restrict__ vresmaxs,
                          const float* __restrict__ vlomaxs,
                          int* __restrict__ assign, int* __restrict__ refine_cnt,
                          int* __restrict__ refine_pt) {
    int p = blockIdx.x * 256 + threadIdx.x;
    int b = p >> 14;
    float bv1 = 3.4e38f, bv2 = 3.4e38f; int bi1 = 0x7fffffff, bi2 = 0x7fffffff;
    #pragma unroll
    for (int ch = 0; ch < 4; ch++) {
        float2 vv = pvals[(size_t)p * 4 + ch];
        int2 ii = pinds[(size_t)p * 4 + ch];
        if (vv.x < bv1 || (vv.x == bv1 && ii.x < bi1)) {
            if (bv1 < vv.y || (bv1 == vv.y && bi1 < ii.y)) { bv2 = bv1; bi2 = bi1; }
            else { bv2 = vv.y; bi2 = ii.y; }
            bv1 = vv.x; bi1 = ii.x;
        } else if (vv.x < bv2 || (vv.x == bv2 && ii.x < bi2)) {
            bv2 = vv.x; bi2 = ii.x;
        }
    }
    assign[p] = bi1;
    // |dot err| <= xres*||v||max + ||x||*vresmax + xlo*vlomax (dropped xl*vl) [+ MFMA ~4e-4]
    float thr = 4.0f * (xres[p] * vmaxs[b] + sqrtf(x2[p]) * vresmaxs[b]
                        + xlo[p] * vlomaxs[b]) + 4e-3f;
    if (bv2 - bv1 < thr) {
        int pos = atomicAdd(refine_cnt, 1);
        refine_pt[pos] = p;
    }
}

// exact fp32 rescan over ALL 512 centers for flagged points (block per point, coalesced vT)
__global__ __launch_bounds__(256) void k_rescan(
    const float* __restrict__ x, const float* __restrict__ vT,
    const float* __restrict__ x2, const float* __restrict__ v2,
    const int* __restrict__ refine_cnt, const int* __restrict__ refine_pt,
    int* __restrict__ assign) {
    __shared__ float xs[256];
    __shared__ float rv[256];
    __shared__ int ri[256];
    int cnt = *refine_cnt;
    int t = threadIdx.x;
    for (int i = blockIdx.x; i < cnt; i += gridDim.x) {
        int p = refine_pt[i];
        int b = p >> 14;
        xs[t] = x[(size_t)p * D + t];
        __syncthreads();
        const float* vtb = vT + (size_t)b * D * K;
        float s0 = 0.f, s1 = 0.f;
        for (int d = 0; d < D; d++) {
            float xd = xs[d];
            s0 = fmaf(xd, vtb[(size_t)d * K + t], s0);
            s1 = fmaf(xd, vtb[(size_t)d * K + 256 + t], s1);
        }
        float x2p = x2[p];
        float d0 = fmaxf((x2p - 2.0f * s0) + v2[b * K + t], 0.0f);
        float d1 = fmaxf((x2p - 2.0f * s1) + v2[b * K + 256 + t], 0.0f);
        float bv; int bi;
        if (d1 < d0) { bv = d1; bi = t + 256; } else { bv = d0; bi = t; }
        rv[t] = bv; ri[t] = bi;
        __syncthreads();
        for (int s = 128; s; s >>= 1) {
            if (t < s) {
                if (rv[t + s] < rv[t] || (rv[t + s] == rv[t] && ri[t + s] < ri[t])) {
                    rv[t] = rv[t + s]; ri[t] = ri[t + s];
                }
            }
            __syncthreads();
        }
        if (t == 0) assign[p] = ri[0];
        __syncthreads();
    }
}

// =================== membership -> new centers (proven) ===================

__global__ void k_count(const int* __restrict__ assign, int* __restrict__ counts) {
    int idx = blockIdx.x * 256 + threadIdx.x;
    int b = idx / N;
    int a = assign[idx];
    atomicAdd(&counts[b * K + a], 1);
}

__global__ __launch_bounds__(256) void k_scatter(
    const int* __restrict__ assign, const int* __restrict__ counts,
    int* __restrict__ cursor, int* __restrict__ order) {
    __shared__ int offs[K];
    int b = blockIdx.y;
    if (threadIdx.x < 64) {
        int lane = threadIdx.x;
        int pre[8]; int s = 0;
        #pragma unroll
        for (int j = 0; j < 8; j++) { pre[j] = s; s += counts[b * K + lane * 8 + j]; }
        int inc = s;
        #pragma unroll
        for (int off = 1; off < 64; off <<= 1) {
            int o = __shfl_up(inc, off);
            if (lane >= off) inc += o;
        }
        int excl = inc - s;
        #pragma unroll
        for (int j = 0; j < 8; j++) offs[lane * 8 + j] = excl + pre[j];
    }
    __syncthreads();
    int n = blockIdx.x * 256 + threadIdx.x;
    int a = assign[b * N + n];
    int pos = atomicAdd(&cursor[b * K + a], 1);
    order[b * N + offs[a] + pos] = n;
}

__global__ __launch_bounds__(256) void k_sumdiv(
    const float* __restrict__ x, const int* __restrict__ counts,
    const int* __restrict__ order, const float* __restrict__ totsum,
    float* __restrict__ v) {
    __shared__ int sh[256];
    __shared__ int ord[256];
    int t = threadIdx.x;
    int b = blockIdx.y, k = blockIdx.x;
    const int* cb = counts + b * K;
    int partial = 0;
    for (int j = t; j < k; j += 256) partial += cb[j];
    sh[t] = partial; __syncthreads();
    for (int s = 128; s; s >>= 1) { if (t < s) sh[t] += sh[t + s]; __syncthreads(); }
    int off = sh[0];
    int cnt = cb[k];
    const float* xb = x + (size_t)b * N * D;
    float acc = 0.f;
    for (int m0 = 0; m0 < cnt; m0 += 256) {
        int mm = min(256, cnt - m0);
        if (t < mm) ord[t] = order[b * N + off + m0 + t];
        __syncthreads();
        for (int m = 0; m < mm; m++) {
            int n = ord[m];
            acc += xb[(size_t)n * D + t];
        }
        __syncthreads();
    }
    float out;
    if (cnt > 0) out = acc * (1.0f / (float)cnt);
    else out = totsum[b * D + t];
    v[((size_t)b * K + k) * D + t] = out;
}

__global__ void k_write_u(const int* __restrict__ assign, float* __restrict__ uout) {
    int idx = blockIdx.x * 256 + threadIdx.x;
    int a = assign[idx];
    uout[(size_t)idx * K + a] = 1.0f;
}

__global__ void k_copy_v(const float* __restrict__ v, float* __restrict__ out) {
    int idx = blockIdx.x * 256 + threadIdx.x;
    ((float4*)out)[idx] = ((const float4*)v)[idx];
}

extern "C" void kernel_launch(void* const* d_in, const int* in_sizes, int n_in,
                              void* d_out, int out_size, void* d_ws, size_t ws_size,
                              hipStream_t stream) {
    const float* x = (const float*)d_in[0];
    float* out = (float*)d_out;
    char* ws = (char*)d_ws;

    // ---- ws: proven-small footprint (<3.0 MB) ----
    size_t off = 0;
    float* v      = (float*)(ws + off); off += (size_t)B * K * D * 4;
    float* x2     = (float*)(ws + off); off += (size_t)B * N * 4;
    float* v2     = (float*)(ws + off); off += (size_t)B * K * 4;
    float* totsum = (float*)(ws + off); off += (size_t)B * D * 4;
    int* assign   = (int*)(ws + off);   off += (size_t)B * N * 4;
    int* counts   = (int*)(ws + off);   off += (size_t)B * K * 4;   // counts+cursor contiguous
    int* cursor   = (int*)(ws + off);   off += (size_t)B * K * 4;
    int* order    = (int*)(ws + off);   off += (size_t)B * N * 4;
    int* inds     = (int*)(ws + off);   off += 4096;
    int* refine_cnt = (int*)(ws + off); off += 256;

    // ---- big scratch in d_out u-region (134 MB; r4/r6/r7-proven home) ----
    char* ob = (char*)out;
    size_t oboff = 0;
    unsigned short* xcat = (unsigned short*)(ob + oboff); oboff += (size_t)B * N * 512 * 2;  // 64 MiB
    float2* pvals  = (float2*)(ob + oboff); oboff += (size_t)B * N * 4 * sizeof(float2);     // 2 MiB
    int2* pinds    = (int2*)(ob + oboff);   oboff += (size_t)B * N * 4 * sizeof(int2);       // 2 MiB
    int* refine_pt = (int*)(ob + oboff);    oboff += (size_t)B * N * 4;                      // 256 KiB
    float* vT      = (float*)(ob + oboff);  oboff += (size_t)B * K * D * 4;                  // 2 MiB
    float* xres    = (float*)(ob + oboff);  oboff += (size_t)B * N * 4;                      // 256 KiB
    float* xlo     = (float*)(ob + oboff);  oboff += (size_t)B * N * 4;                      // 256 KiB
    float* vres    = (float*)(ob + oboff);  oboff += (size_t)B * K * 4;                      // 8 KiB
    float* vlo     = (float*)(ob + oboff);  oboff += (size_t)B * K * 4;                      // 8 KiB
    float* vmaxs   = (float*)(ob + oboff);  oboff += 256;
    float* vresmaxs = (float*)(ob + oboff); oboff += 256;
    float* vlomaxs = (float*)(ob + oboff);  oboff += 256;
    unsigned short* vcat = (unsigned short*)(out + (size_t)B * N * K);  // v-region, 2 MiB exact

    static int h_inds[K];
    host_sample_inds(h_inds);
    hipMemcpyAsync(inds, h_inds, K * sizeof(int), hipMemcpyHostToDevice, stream);

    hipMemsetAsync(totsum, 0, (size_t)B * D * 4, stream);
    k_gather_v0<<<B * K, 64, 0, stream>>>(x, inds, v);
    k_totsum<<<dim3(64, B), 256, 0, stream>>>(x, totsum);
    k_prep<<<(B * N) / 4, 256, 0, stream>>>(x, xcat, x2, xres, xlo);

    for (int it = 0; it < ITERS; it++) {
        k_prep<<<(B * K) / 4, 256, 0, stream>>>(v, vcat, v2, vres, vlo);
        k_errmax<<<B, 256, 0, stream>>>(v2, vres, vlo, vmaxs, vresmaxs, vlomaxs);
        k_transpose<<<(B * K * D) / 256, 256, 0, stream>>>(v, vT);
        k_gemm_assign<<<dim3(N / 128, K / 128, B), 256, 0, stream>>>(
            xcat, vcat, x2, v2, pvals, pinds);
        hipMemsetAsync(refine_cnt, 0, 256, stream);
        k_reduce2<<<(B * N) / 256, 256, 0, stream>>>(pvals, pinds, x2, xres, xlo,
                                                     vmaxs, vresmaxs, vlomaxs,
                                                     assign, refine_cnt, refine_pt);
        k_rescan<<<1024, 256, 0, stream>>>(x, vT, x2, v2, refine_cnt, refine_pt, assign);
        hipMemsetAsync(counts, 0, 2 * (size_t)B * K * 4, stream);
        k_count<<<(B * N) / 256, 256, 0, stream>>>(assign, counts);
        k_scatter<<<dim3(N / 256, B), 256, 0, stream>>>(assign, counts, cursor, order);
        k_sumdiv<<<dim3(K, B), 256, 0, stream>>>(x, counts, order, totsum, v);
    }

    hipMemsetAsync(out, 0, (size_t)B * N * K * 4, stream);
    k_write_u<<<(B * N) / 256, 256, 0, stream>>>(assign, out);
    k_copy_v<<<(B * K * D) / 1024, 256, 0, stream>>>(v, out + (size_t)B * N * K);
}

// Round 9
// 2254.268 us; speedup vs baseline: 1.0359x; 1.0359x over previous
//
#include <hip/hip_runtime.h>
#include <string.h>

#define B 4
#define N 16384
#define D 256
#define K 512
#define ITERS 10

typedef short short8 __attribute__((ext_vector_type(8)));
typedef float float4v __attribute__((ext_vector_type(4)));

// ---------------- host MT19937 exactly matching CPython random.seed(42); random.sample(range(16384), 512)
static void host_sample_inds(int* out) {
    static unsigned int mt[624];
    mt[0] = 19650218u;
    for (int i = 1; i < 624; i++)
        mt[i] = 1812433253u * (mt[i - 1] ^ (mt[i - 1] >> 30)) + (unsigned)i;
    {
        int i = 1, j = 0;
        for (int kk = 624; kk; kk--) {
            mt[i] = (mt[i] ^ ((mt[i - 1] ^ (mt[i - 1] >> 30)) * 1664525u)) + 42u + (unsigned)j;
            i++; j++;
            if (i >= 624) { mt[0] = mt[623]; i = 1; }
            if (j >= 1) j = 0;
        }
        for (int kk = 623; kk; kk--) {
            mt[i] = (mt[i] ^ ((mt[i - 1] ^ (mt[i - 1] >> 30)) * 1566083941u)) - (unsigned)i;
            i++;
            if (i >= 624) { mt[0] = mt[623]; i = 1; }
        }
        mt[0] = 0x80000000u;
    }
    static unsigned char seen[N];
    memset(seen, 0, sizeof(seen));
    int mti = 624;
    int got = 0;
    while (got < K) {
        if (mti >= 624) {
            for (int kk = 0; kk < 624; kk++) {
                unsigned int yy = (mt[kk] & 0x80000000u) | (mt[(kk + 1) % 624] & 0x7fffffffu);
                mt[kk] = mt[(kk + 397) % 624] ^ (yy >> 1) ^ ((yy & 1u) ? 0x9908b0dfu : 0u);
            }
            mti = 0;
        }
        unsigned int y = mt[mti++];
        y ^= y >> 11; y ^= (y << 7) & 0x9d2c5680u; y ^= (y << 15) & 0xefc60000u; y ^= y >> 18;
        unsigned int r = y >> 17;
        if (r >= (unsigned)N) continue;
        if (seen[r]) continue;
        seen[r] = 1;
        out[got++] = (int)r;
    }
}

__device__ inline void gload_lds16(const void* g, void* l) {
    __builtin_amdgcn_global_load_lds((const __attribute__((address_space(1))) void*)g,
                                     (__attribute__((address_space(3))) void*)l, 16, 0, 0);
}

__device__ inline unsigned bf16_rne(float f) {
    unsigned u = __float_as_uint(f);
    return (u + 0x7fffu + ((u >> 16) & 1u)) >> 16;
}

// =================== prep ===================

__global__ void k_gather_v0(const float* __restrict__ x, const int* __restrict__ inds,
                            float* __restrict__ v) {
    int bk = blockIdx.x; int b = bk / K, k = bk % K;
    int n = inds[k];
    const float4* src = (const float4*)(x + ((size_t)b * N + n) * D);
    float4* dst = (float4*)(v + ((size_t)b * K + k) * D);
    dst[threadIdx.x] = src[threadIdx.x];
}

__global__ void k_totsum(const float* __restrict__ x, float* __restrict__ totsum) {
    int b = blockIdx.y;
    int n0 = blockIdx.x * (N / 64);
    int t = threadIdx.x;
    const float* xb = x + (size_t)b * N * D;
    float s = 0.f;
    for (int n = n0; n < n0 + N / 64; n++) s += xb[(size_t)n * D + t];
    atomicAdd(&totsum[b * D + t], s);
}

// fused: rownorm + bf16 split + residual norm + lo norm. wave per row.
__global__ void k_prep(const float* __restrict__ src, unsigned short* __restrict__ cat,
                       float* __restrict__ sq, float* __restrict__ resn,
                       float* __restrict__ lon) {
    int wave = threadIdx.x >> 6, lane = threadIdx.x & 63;
    int row = blockIdx.x * 4 + wave;
    float4 f = ((const float4*)(src + (size_t)row * D))[lane];
    float comp[4] = {f.x, f.y, f.z, f.w};
    unsigned short h[4], l[4];
    float r2 = 0.f, l2 = 0.f, n2 = 0.f;
    #pragma unroll
    for (int j = 0; j < 4; j++) {
        n2 += comp[j] * comp[j];
        unsigned hi = bf16_rne(comp[j]);
        float hif = __uint_as_float(hi << 16);
        float r = comp[j] - hif;            // exact in fp32
        unsigned lo = bf16_rne(r);
        float lof = __uint_as_float(lo << 16);
        float res = r - lof;                // dropped residual
        r2 += res * res;
        l2 += lof * lof;
        h[j] = (unsigned short)hi; l[j] = (unsigned short)lo;
    }
    unsigned short* orow = cat + (size_t)row * 512;
    *(ushort4*)&orow[lane * 4] = make_ushort4(h[0], h[1], h[2], h[3]);
    *(ushort4*)&orow[256 + lane * 4] = make_ushort4(l[0], l[1], l[2], l[3]);
    #pragma unroll
    for (int off = 32; off; off >>= 1) {
        r2 += __shfl_xor(r2, off);
        l2 += __shfl_xor(l2, off);
        n2 += __shfl_xor(n2, off);
    }
    if (lane == 0) { sq[row] = n2; resn[row] = sqrtf(r2); lon[row] = sqrtf(l2); }
}

// per-batch maxes: ||v||, ||v residual||, ||v lo||
__global__ void k_errmax(const float* __restrict__ v2, const float* __restrict__ vres,
                         const float* __restrict__ vlo,
                         float* __restrict__ vmaxs, float* __restrict__ vresmaxs,
                         float* __restrict__ vlomaxs) {
    __shared__ float s1[256], s2[256], s3[256];
    int b = blockIdx.x, t = threadIdx.x;
    s1[t] = fmaxf(sqrtf(v2[b * K + t]), sqrtf(v2[b * K + 256 + t]));
    s2[t] = fmaxf(vres[b * K + t], vres[b * K + 256 + t]);
    s3[t] = fmaxf(vlo[b * K + t], vlo[b * K + 256 + t]);
    __syncthreads();
    for (int s = 128; s; s >>= 1) {
        if (t < s) {
            s1[t] = fmaxf(s1[t], s1[t + s]);
            s2[t] = fmaxf(s2[t], s2[t + s]);
            s3[t] = fmaxf(s3[t], s3[t + s]);
        }
        __syncthreads();
    }
    if (t == 0) { vmaxs[b] = s1[0]; vresmaxs[b] = s2[0]; vlomaxs[b] = s3[0]; }
}

__global__ void k_transpose(const float* __restrict__ v, float* __restrict__ vT) {
    int idx = blockIdx.x * 256 + threadIdx.x;   // B*K*D
    int d = idx & 255, c = (idx >> 8) & 511, b = idx >> 17;
    vT[((size_t)b * D + d) * K + c] = v[idx];
}

// =================== fused MFMA GEMM + per-block top-2 ===================
// r6 staging (global_load_lds for A AND B, XOR swizzle, 2 barriers/kt — fastest measured)
// x 12-step schedule (xh*vh 0-3, xh*vl 4-7, xl*vh 8-11; xl*vl covered by flag bound —
// numerics validated r7/r8).
__global__ __launch_bounds__(256) void k_gemm_assign(
    const unsigned short* __restrict__ xcat, const unsigned short* __restrict__ vcat,
    const float* __restrict__ x2, const float* __restrict__ v2,
    float2* __restrict__ pvals, int2* __restrict__ pinds) {
    __shared__ __align__(16) unsigned short As[128 * 64];
    __shared__ __align__(16) unsigned short Bs[128 * 64];
    __shared__ float x2s[128], v2s[128];
    __shared__ float candv[128][2][2];
    __shared__ int candi[128][2][2];
    int b = blockIdx.z, ch = blockIdx.y;
    int n0 = blockIdx.x * 128;
    int tid = threadIdx.x;
    int wv = tid >> 6, lane = tid & 63;
    int wr = wv >> 1, wc = wv & 1;
    int quad = lane >> 4, l16 = lane & 15;
    const unsigned short* xb = xcat + ((size_t)b * N + n0) * 512;
    const unsigned short* vb = vcat + ((size_t)b * K + ch * 128) * 512;

    if (tid < 128) {
        x2s[tid] = x2[b * N + n0 + tid];
        v2s[tid] = v2[b * K + ch * 128 + tid];
    }

    float4v acc[4][4];
    #pragma unroll
    for (int i = 0; i < 4; i++)
        #pragma unroll
        for (int j = 0; j < 4; j++) acc[i][j] = (float4v){0.f, 0.f, 0.f, 0.f};

    for (int kt = 0; kt < 12; kt++) {
        int k4 = (kt & 3) * 64;
        int kcolA = (kt < 8) ? k4 : 256 + k4;                    // xh,xh,xl
        int kcolB = (kt < 4) ? k4 : ((kt < 8) ? 256 + k4 : k4);  // vh,vl,vh
        __syncthreads();
        #pragma unroll
        for (int i = 0; i < 4; i++) {
            int l = i * 256 + wv * 64 + lane;
            int row = l >> 3, cc = l & 7;
            int c = cc ^ (row & 7);
            gload_lds16(xb + (size_t)row * 512 + kcolA + c * 8,
                        (void*)&As[(size_t)(i * 256 + wv * 64) * 8]);
        }
        #pragma unroll
        for (int i = 0; i < 4; i++) {
            int l = i * 256 + wv * 64 + lane;
            int row = l >> 3, cc = l & 7;
            int c = cc ^ (row & 7);
            gload_lds16(vb + (size_t)row * 512 + kcolB + c * 8,
                        (void*)&Bs[(size_t)(i * 256 + wv * 64) * 8]);
        }
        __syncthreads();
        #pragma unroll
        for (int ks = 0; ks < 2; ks++) {
            short8 af[4], bf[4];
            int ccr = ks * 4 + quad;
            #pragma unroll
            for (int f = 0; f < 4; f++) {
                int rA = wr * 64 + f * 16 + l16;
                af[f] = *(const short8*)&As[(rA * 8 + (ccr ^ (rA & 7))) * 8];
                int rB = wc * 64 + f * 16 + l16;
                bf[f] = *(const short8*)&Bs[(rB * 8 + (ccr ^ (rB & 7))) * 8];
            }
            #pragma unroll
            for (int fi = 0; fi < 4; fi++)
                #pragma unroll
                for (int fj = 0; fj < 4; fj++)
                    acc[fi][fj] = __builtin_amdgcn_mfma_f32_16x16x32_bf16(
                        af[fi], bf[fj], acc[fi][fj], 0, 0, 0);
        }
    }

    // epilogue: per-row top-2 over this block's 128 centers (r6-validated verbatim)
    #pragma unroll
    for (int fi = 0; fi < 4; fi++) {
        #pragma unroll
        for (int r = 0; r < 4; r++) {
            int lrow = wr * 64 + fi * 16 + quad * 4 + r;
            float x2v = x2s[lrow];
            float bv1 = 3.4e38f, bv2 = 3.4e38f; int bi1 = 0x7fffffff, bi2 = 0x7fffffff;
            #pragma unroll
            for (int fj = 0; fj < 4; fj++) {
                int lcol = wc * 64 + fj * 16 + l16;
                float dist = fmaxf((x2v - 2.0f * acc[fi][fj][r]) + v2s[lcol], 0.0f);
                int cg = ch * 128 + lcol;
                if (dist < bv1 || (dist == bv1 && cg < bi1)) {
                    bv2 = bv1; bi2 = bi1; bv1 = dist; bi1 = cg;
                } else if (dist < bv2 || (dist == bv2 && cg < bi2)) {
                    bv2 = dist; bi2 = cg;
                }
            }
            #pragma unroll
            for (int off = 1; off < 16; off <<= 1) {
                float ov1 = __shfl_xor(bv1, off); int oi1 = __shfl_xor(bi1, off);
                float ov2 = __shfl_xor(bv2, off); int oi2 = __shfl_xor(bi2, off);
                if (ov1 < bv1 || (ov1 == bv1 && oi1 < bi1)) {
                    float nv2; int ni2;
                    if (bv1 < ov2 || (bv1 == ov2 && bi1 < oi2)) { nv2 = bv1; ni2 = bi1; }
                    else { nv2 = ov2; ni2 = oi2; }
                    bv1 = ov1; bi1 = oi1; bv2 = nv2; bi2 = ni2;
                } else if (ov1 < bv2 || (ov1 == bv2 && oi1 < bi2)) {
                    bv2 = ov1; bi2 = oi1;
                }
            }
            if (l16 == 0) {
                candv[lrow][wc][0] = bv1; candv[lrow][wc][1] = bv2;
                candi[lrow][wc][0] = bi1; candi[lrow][wc][1] = bi2;
            }
        }
    }
    __syncthreads();
    if (tid < 128) {
        float a1 = candv[tid][0][0], a2 = candv[tid][0][1];
        int   j1 = candi[tid][0][0], j2 = candi[tid][0][1];
        float o1 = candv[tid][1][0], o2 = candv[tid][1][1];
        int   p1 = candi[tid][1][0], p2 = candi[tid][1][1];
        float bv1, bv2; int bi1, bi2;
        if (o1 < a1 || (o1 == a1 && p1 < j1)) {
            bv1 = o1; bi1 = p1;
            if (a1 < o2 || (a1 == o2 && j1 < p2)) { bv2 = a1; bi2 = j1; }
            else { bv2 = o2; bi2 = p2; }
        } else {
            bv1 = a1; bi1 = j1;
            if (o1 < a2 || (o1 == a2 && p1 < j2)) { bv2 = o1; bi2 = p1; }
            else { bv2 = a2; bi2 = j2; }
        }
        size_t p = (size_t)(b * N + n0 + tid);
        pvals[p * 4 + ch] = make_float2(bv1, bv2);
        pinds[p * 4 + ch] = make_int2(bi1, bi2);
    }
}

// merge 4 chunk top-2s -> assign; flag points whose margin < rigorous error bound
__global__ void k_reduce2(const float2* __restrict__ pvals, const int2* __restrict__ pinds,
                          const float* __restrict__ x2, const float* __restrict__ xres,
                          const float* __restrict__ xlo,
                          const float* __restrict__ vmaxs, const float* __restrict__ vresmaxs,
                          const float* __restrict__ vlomaxs,
                          int* __restrict__ assign, int* __restrict__ refine_cnt,
                          int* __restrict__ refine_pt) {
    int p = blockIdx.x * 256 + threadIdx.x;
    int b = p >> 14;
    float bv1 = 3.4e38f, bv2 = 3.4e38f; int bi1 = 0x7fffffff, bi2 = 0x7fffffff;
    #pragma unroll
    for (int ch = 0; ch < 4; ch++) {
        float2 vv = pvals[(size_t)p * 4 + ch];
        int2 ii = pinds[(size_t)p * 4 + ch];
        if (vv.x < bv1 || (vv.x == bv1 && ii.x < bi1)) {
            if (bv1 < vv.y || (bv1 == vv.y && bi1 < ii.y)) { bv2 = bv1; bi2 = bi1; }
            else { bv2 = vv.y; bi2 = ii.y; }
            bv1 = vv.x; bi1 = ii.x;
        } else if (vv.x < bv2 || (vv.x == bv2 && ii.x < bi2)) {
            bv2 = vv.x; bi2 = ii.x;
        }
    }
    assign[p] = bi1;
    // |dot err| <= xres*||v||max + ||x||*vresmax + xlo*vlomax (dropped xl*vl) [+ MFMA ~4e-4]
    float thr = 4.0f * (xres[p] * vmaxs[b] + sqrtf(x2[p]) * vresmaxs[b]
                        + xlo[p] * vlomaxs[b]) + 4e-3f;
    if (bv2 - bv1 < thr) {
        int pos = atomicAdd(refine_cnt, 1);
        refine_pt[pos] = p;
    }
}

// exact fp32 rescan over ALL 512 centers for flagged points (block per point, coalesced vT)
__global__ __launch_bounds__(256) void k_rescan(
    const float* __restrict__ x, const float* __restrict__ vT,
    const float* __restrict__ x2, const float* __restrict__ v2,
    const int* __restrict__ refine_cnt, const int* __restrict__ refine_pt,
    int* __restrict__ assign) {
    __shared__ float xs[256];
    __shared__ float rv[256];
    __shared__ int ri[256];
    int cnt = *refine_cnt;
    int t = threadIdx.x;
    for (int i = blockIdx.x; i < cnt; i += gridDim.x) {
        int p = refine_pt[i];
        int b = p >> 14;
        xs[t] = x[(size_t)p * D + t];
        __syncthreads();
        const float* vtb = vT + (size_t)b * D * K;
        float s0 = 0.f, s1 = 0.f;
        for (int d = 0; d < D; d++) {
            float xd = xs[d];
            s0 = fmaf(xd, vtb[(size_t)d * K + t], s0);
            s1 = fmaf(xd, vtb[(size_t)d * K + 256 + t], s1);
        }
        float x2p = x2[p];
        float d0 = fmaxf((x2p - 2.0f * s0) + v2[b * K + t], 0.0f);
        float d1 = fmaxf((x2p - 2.0f * s1) + v2[b * K + 256 + t], 0.0f);
        float bv; int bi;
        if (d1 < d0) { bv = d1; bi = t + 256; } else { bv = d0; bi = t; }
        rv[t] = bv; ri[t] = bi;
        __syncthreads();
        for (int s = 128; s; s >>= 1) {
            if (t < s) {
                if (rv[t + s] < rv[t] || (rv[t + s] == rv[t] && ri[t + s] < ri[t])) {
                    rv[t] = rv[t + s]; ri[t] = ri[t + s];
                }
            }
            __syncthreads();
        }
        if (t == 0) assign[p] = ri[0];
        __syncthreads();
    }
}

// =================== membership -> new centers (proven) ===================

__global__ void k_count(const int* __restrict__ assign, int* __restrict__ counts) {
    int idx = blockIdx.x * 256 + threadIdx.x;
    int b = idx / N;
    int a = assign[idx];
    atomicAdd(&counts[b * K + a], 1);
}

__global__ __launch_bounds__(256) void k_scatter(
    const int* __restrict__ assign, const int* __restrict__ counts,
    int* __restrict__ cursor, int* __restrict__ order) {
    __shared__ int offs[K];
    int b = blockIdx.y;
    if (threadIdx.x < 64) {
        int lane = threadIdx.x;
        int pre[8]; int s = 0;
        #pragma unroll
        for (int j = 0; j < 8; j++) { pre[j] = s; s += counts[b * K + lane * 8 + j]; }
        int inc = s;
        #pragma unroll
        for (int off = 1; off < 64; off <<= 1) {
            int o = __shfl_up(inc, off);
            if (lane >= off) inc += o;
        }
        int excl = inc - s;
        #pragma unroll
        for (int j = 0; j < 8; j++) offs[lane * 8 + j] = excl + pre[j];
    }
    __syncthreads();
    int n = blockIdx.x * 256 + threadIdx.x;
    int a = assign[b * N + n];
    int pos = atomicAdd(&cursor[b * K + a], 1);
    order[b * N + offs[a] + pos] = n;
}

__global__ __launch_bounds__(256) void k_sumdiv(
    const float* __restrict__ x, const int* __restrict__ counts,
    const int* __restrict__ order, const float* __restrict__ totsum,
    float* __restrict__ v) {
    __shared__ int sh[256];
    __shared__ int ord[256];
    int t = threadIdx.x;
    int b = blockIdx.y, k = blockIdx.x;
    const int* cb = counts + b * K;
    int partial = 0;
    for (int j = t; j < k; j += 256) partial += cb[j];
    sh[t] = partial; __syncthreads();
    for (int s = 128; s; s >>= 1) { if (t < s) sh[t] += sh[t + s]; __syncthreads(); }
    int off = sh[0];
    int cnt = cb[k];
    const float* xb = x + (size_t)b * N * D;
    float acc = 0.f;
    for (int m0 = 0; m0 < cnt; m0 += 256) {
        int mm = min(256, cnt - m0);
        if (t < mm) ord[t] = order[b * N + off + m0 + t];
        __syncthreads();
        for (int m = 0; m < mm; m++) {
            int n = ord[m];
            acc += xb[(size_t)n * D + t];
        }
        __syncthreads();
    }
    float out;
    if (cnt > 0) out = acc * (1.0f / (float)cnt);
    else out = totsum[b * D + t];
    v[((size_t)b * K + k) * D + t] = out;
}

__global__ void k_write_u(const int* __restrict__ assign, float* __restrict__ uout) {
    int idx = blockIdx.x * 256 + threadIdx.x;
    int a = assign[idx];
    uout[(size_t)idx * K + a] = 1.0f;
}

__global__ void k_copy_v(const float* __restrict__ v, float* __restrict__ out) {
    int idx = blockIdx.x * 256 + threadIdx.x;
    ((float4*)out)[idx] = ((const float4*)v)[idx];
}

extern "C" void kernel_launch(void* const* d_in, const int* in_sizes, int n_in,
                              void* d_out, int out_size, void* d_ws, size_t ws_size,
                              hipStream_t stream) {
    const float* x = (const float*)d_in[0];
    float* out = (float*)d_out;
    char* ws = (char*)d_ws;

    // ---- ws: proven-small footprint (<3.0 MB) ----
    size_t off = 0;
    float* v      = (float*)(ws + off); off += (size_t)B * K * D * 4;
    float* x2     = (float*)(ws + off); off += (size_t)B * N * 4;
    float* v2     = (float*)(ws + off); off += (size_t)B * K * 4;
    float* totsum = (float*)(ws + off); off += (size_t)B * D * 4;
    int* assign   = (int*)(ws + off);   off += (size_t)B * N * 4;
    int* counts   = (int*)(ws + off);   off += (size_t)B * K * 4;   // counts+cursor contiguous
    int* cursor   = (int*)(ws + off);   off += (size_t)B * K * 4;
    int* order    = (int*)(ws + off);   off += (size_t)B * N * 4;
    int* inds     = (int*)(ws + off);   off += 4096;
    int* refine_cnt = (int*)(ws + off); off += 256;

    // ---- big scratch in d_out u-region (134 MB; r4/r6/r7/r8-proven home) ----
    char* ob = (char*)out;
    size_t oboff = 0;
    unsigned short* xcat = (unsigned short*)(ob + oboff); oboff += (size_t)B * N * 512 * 2;  // 64 MiB
    float2* pvals  = (float2*)(ob + oboff); oboff += (size_t)B * N * 4 * sizeof(float2);     // 2 MiB
    int2* pinds    = (int2*)(ob + oboff);   oboff += (size_t)B * N * 4 * sizeof(int2);       // 2 MiB
    int* refine_pt = (int*)(ob + oboff);    oboff += (size_t)B * N * 4;                      // 256 KiB
    float* vT      = (float*)(ob + oboff);  oboff += (size_t)B * K * D * 4;                  // 2 MiB
    float* xres    = (float*)(ob + oboff);  oboff += (size_t)B * N * 4;                      // 256 KiB
    float* xlo     = (float*)(ob + oboff);  oboff += (size_t)B * N * 4;                      // 256 KiB
    float* vres    = (float*)(ob + oboff);  oboff += (size_t)B * K * 4;                      // 8 KiB
    float* vlo     = (float*)(ob + oboff);  oboff += (size_t)B * K * 4;                      // 8 KiB
    float* vmaxs   = (float*)(ob + oboff);  oboff += 256;
    float* vresmaxs = (float*)(ob + oboff); oboff += 256;
    float* vlomaxs = (float*)(ob + oboff);  oboff += 256;
    unsigned short* vcat = (unsigned short*)(out + (size_t)B * N * K);  // v-region, 2 MiB exact

    static int h_inds[K];
    host_sample_inds(h_inds);
    hipMemcpyAsync(inds, h_inds, K * sizeof(int), hipMemcpyHostToDevice, stream);

    hipMemsetAsync(totsum, 0, (size_t)B * D * 4, stream);
    k_gather_v0<<<B * K, 64, 0, stream>>>(x, inds, v);
    k_totsum<<<dim3(64, B), 256, 0, stream>>>(x, totsum);
    k_prep<<<(B * N) / 4, 256, 0, stream>>>(x, xcat, x2, xres, xlo);

    for (int it = 0; it < ITERS; it++) {
        k_prep<<<(B * K) / 4, 256, 0, stream>>>(v, vcat, v2, vres, vlo);
        k_errmax<<<B, 256, 0, stream>>>(v2, vres, vlo, vmaxs, vresmaxs, vlomaxs);
        k_transpose<<<(B * K * D) / 256, 256, 0, stream>>>(v, vT);
        k_gemm_assign<<<dim3(N / 128, K / 128, B), 256, 0, stream>>>(
            xcat, vcat, x2, v2, pvals, pinds);
        hipMemsetAsync(refine_cnt, 0, 256, stream);
        k_reduce2<<<(B * N) / 256, 256, 0, stream>>>(pvals, pinds, x2, xres, xlo,
                                                     vmaxs, vresmaxs, vlomaxs,
                                                     assign, refine_cnt, refine_pt);
        k_rescan<<<1024, 256, 0, stream>>>(x, vT, x2, v2, refine_cnt, refine_pt, assign);
        hipMemsetAsync(counts, 0, 2 * (size_t)B * K * 4, stream);
        k_count<<<(B * N) / 256, 256, 0, stream>>>(assign, counts);
        k_scatter<<<dim3(N / 256, B), 256, 0, stream>>>(assign, counts, cursor, order);
        k_sumdiv<<<dim3(K, B), 256, 0, stream>>>(x, counts, order, totsum, v);
    }

    hipMemsetAsync(out, 0, (size_t)B * N * K * 4, stream);
    k_write_u<<<(B * N) / 256, 256, 0, stream>>>(assign, out);
    k_copy_v<<<(B * K * D) / 1024, 256, 0, stream>>>(v, out + (size_t)B * N * K);
}

// Round 10
// 2213.166 us; speedup vs baseline: 1.0551x; 1.0186x over previous
//
#include <hip/hip_runtime.h>
#include <string.h>

#define B 4
#define N 16384
#define D 256
#define K 512
#define ITERS 10

typedef short short8 __attribute__((ext_vector_type(8)));
typedef float float4v __attribute__((ext_vector_type(4)));

// ---------------- host MT19937 exactly matching CPython random.seed(42); random.sample(range(16384), 512)
static void host_sample_inds(int* out) {
    static unsigned int mt[624];
    mt[0] = 19650218u;
    for (int i = 1; i < 624; i++)
        mt[i] = 1812433253u * (mt[i - 1] ^ (mt[i - 1] >> 30)) + (unsigned)i;
    {
        int i = 1, j = 0;
        for (int kk = 624; kk; kk--) {
            mt[i] = (mt[i] ^ ((mt[i - 1] ^ (mt[i - 1] >> 30)) * 1664525u)) + 42u + (unsigned)j;
            i++; j++;
            if (i >= 624) { mt[0] = mt[623]; i = 1; }
            if (j >= 1) j = 0;
        }
        for (int kk = 623; kk; kk--) {
            mt[i] = (mt[i] ^ ((mt[i - 1] ^ (mt[i - 1] >> 30)) * 1566083941u)) - (unsigned)i;
            i++;
            if (i >= 624) { mt[0] = mt[623]; i = 1; }
        }
        mt[0] = 0x80000000u;
    }
    static unsigned char seen[N];
    memset(seen, 0, sizeof(seen));
    int mti = 624;
    int got = 0;
    while (got < K) {
        if (mti >= 624) {
            for (int kk = 0; kk < 624; kk++) {
                unsigned int yy = (mt[kk] & 0x80000000u) | (mt[(kk + 1) % 624] & 0x7fffffffu);
                mt[kk] = mt[(kk + 397) % 624] ^ (yy >> 1) ^ ((yy & 1u) ? 0x9908b0dfu : 0u);
            }
            mti = 0;
        }
        unsigned int y = mt[mti++];
        y ^= y >> 11; y ^= (y << 7) & 0x9d2c5680u; y ^= (y << 15) & 0xefc60000u; y ^= y >> 18;
        unsigned int r = y >> 17;
        if (r >= (unsigned)N) continue;
        if (seen[r]) continue;
        seen[r] = 1;
        out[got++] = (int)r;
    }
}

__device__ inline void gload_lds16(const void* g, void* l) {
    __builtin_amdgcn_global_load_lds((const __attribute__((address_space(1))) void*)g,
                                     (__attribute__((address_space(3))) void*)l, 16, 0, 0);
}

__device__ inline unsigned bf16_rne(float f) {
    unsigned u = __float_as_uint(f);
    return (u + 0x7fffu + ((u >> 16) & 1u)) >> 16;
}

// =================== prep ===================

__global__ void k_gather_v0(const float* __restrict__ x, const int* __restrict__ inds,
                            float* __restrict__ v) {
    int bk = blockIdx.x; int b = bk / K, k = bk % K;
    int n = inds[k];
    const float4* src = (const float4*)(x + ((size_t)b * N + n) * D);
    float4* dst = (float4*)(v + ((size_t)b * K + k) * D);
    dst[threadIdx.x] = src[threadIdx.x];
}

__global__ void k_totsum(const float* __restrict__ x, float* __restrict__ totsum) {
    int b = blockIdx.y;
    int n0 = blockIdx.x * (N / 64);
    int t = threadIdx.x;
    const float* xb = x + (size_t)b * N * D;
    float s = 0.f;
    for (int n = n0; n < n0 + N / 64; n++) s += xb[(size_t)n * D + t];
    atomicAdd(&totsum[b * D + t], s);
}

// fused: rownorm + bf16 split + residual norm + lo norm. wave per row.
__global__ void k_prep(const float* __restrict__ src, unsigned short* __restrict__ cat,
                       float* __restrict__ sq, float* __restrict__ resn,
                       float* __restrict__ lon) {
    int wave = threadIdx.x >> 6, lane = threadIdx.x & 63;
    int row = blockIdx.x * 4 + wave;
    float4 f = ((const float4*)(src + (size_t)row * D))[lane];
    float comp[4] = {f.x, f.y, f.z, f.w};
    unsigned short h[4], l[4];
    float r2 = 0.f, l2 = 0.f, n2 = 0.f;
    #pragma unroll
    for (int j = 0; j < 4; j++) {
        n2 += comp[j] * comp[j];
        unsigned hi = bf16_rne(comp[j]);
        float hif = __uint_as_float(hi << 16);
        float r = comp[j] - hif;            // exact in fp32
        unsigned lo = bf16_rne(r);
        float lof = __uint_as_float(lo << 16);
        float res = r - lof;                // dropped residual
        r2 += res * res;
        l2 += lof * lof;
        h[j] = (unsigned short)hi; l[j] = (unsigned short)lo;
    }
    unsigned short* orow = cat + (size_t)row * 512;
    *(ushort4*)&orow[lane * 4] = make_ushort4(h[0], h[1], h[2], h[3]);
    *(ushort4*)&orow[256 + lane * 4] = make_ushort4(l[0], l[1], l[2], l[3]);
    #pragma unroll
    for (int off = 32; off; off >>= 1) {
        r2 += __shfl_xor(r2, off);
        l2 += __shfl_xor(l2, off);
        n2 += __shfl_xor(n2, off);
    }
    if (lane == 0) { sq[row] = n2; resn[row] = sqrtf(r2); lon[row] = sqrtf(l2); }
}

// per-batch maxes: ||v||, ||v residual||, ||v lo||
__global__ void k_errmax(const float* __restrict__ v2, const float* __restrict__ vres,
                         const float* __restrict__ vlo,
                         float* __restrict__ vmaxs, float* __restrict__ vresmaxs,
                         float* __restrict__ vlomaxs) {
    __shared__ float s1[256], s2[256], s3[256];
    int b = blockIdx.x, t = threadIdx.x;
    s1[t] = fmaxf(sqrtf(v2[b * K + t]), sqrtf(v2[b * K + 256 + t]));
    s2[t] = fmaxf(vres[b * K + t], vres[b * K + 256 + t]);
    s3[t] = fmaxf(vlo[b * K + t], vlo[b * K + 256 + t]);
    __syncthreads();
    for (int s = 128; s; s >>= 1) {
        if (t < s) {
            s1[t] = fmaxf(s1[t], s1[t + s]);
            s2[t] = fmaxf(s2[t], s2[t + s]);
            s3[t] = fmaxf(s3[t], s3[t + s]);
        }
        __syncthreads();
    }
    if (t == 0) { vmaxs[b] = s1[0]; vresmaxs[b] = s2[0]; vlomaxs[b] = s3[0]; }
}

__global__ void k_transpose(const float* __restrict__ v, float* __restrict__ vT) {
    int idx = blockIdx.x * 256 + threadIdx.x;   // B*K*D
    int d = idx & 255, c = (idx >> 8) & 511, b = idx >> 17;
    vT[((size_t)b * D + d) * K + c] = v[idx];
}

// =================== fused MFMA GEMM + per-block top-2 ===================
// r9 layout/numerics bit-identical; staging restructured:
//  - double-buffered LDS, prefetch kt+1 issued BEFORE computing kt, ONE barrier per kt
//    (the end-of-kt barrier's vmcnt(0) drain now lands after a full compute phase)
//  - grid: blockIdx.x = ch (fastest) so the 4 blocks sharing an A-tile are temporally
//    adjacent -> A re-reads hit L2/L3 instead of HBM
__global__ __launch_bounds__(256) void k_gemm_assign(
    const unsigned short* __restrict__ xcat, const unsigned short* __restrict__ vcat,
    const float* __restrict__ x2, const float* __restrict__ v2,
    float2* __restrict__ pvals, int2* __restrict__ pinds) {
    __shared__ __align__(16) unsigned short As[2][128 * 64];
    __shared__ __align__(16) unsigned short Bs[2][128 * 64];
    __shared__ float x2s[128], v2s[128];
    __shared__ float candv[128][2][2];
    __shared__ int candi[128][2][2];
    int ch = blockIdx.x, b = blockIdx.z;
    int n0 = blockIdx.y * 128;
    int tid = threadIdx.x;
    int wv = tid >> 6, lane = tid & 63;
    int wr = wv >> 1, wc = wv & 1;
    int quad = lane >> 4, l16 = lane & 15;
    const unsigned short* xb = xcat + ((size_t)b * N + n0) * 512;
    const unsigned short* vb = vcat + ((size_t)b * K + ch * 128) * 512;

    if (tid < 128) {
        x2s[tid] = x2[b * N + n0 + tid];
        v2s[tid] = v2[b * K + ch * 128 + tid];
    }

    // staging meta (r4-validated swizzle): fetch global chunk c into lds slot l
    int lds8[4], srow[4], schunk[4];
    #pragma unroll
    for (int i = 0; i < 4; i++) {
        int l = i * 256 + wv * 64 + lane;
        lds8[i] = l * 8;
        srow[i] = l >> 3;
        schunk[i] = ((l & 7) ^ ((l >> 3) & 7)) * 8;
    }

    float4v acc[4][4];
    #pragma unroll
    for (int i = 0; i < 4; i++)
        #pragma unroll
        for (int j = 0; j < 4; j++) acc[i][j] = (float4v){0.f, 0.f, 0.f, 0.f};

    // kt schedule (r7/r8/r9-validated 12-step): A: xh 0-7, xl 8-11; B: vh 0-3, vl 4-7, vh 8-11
    // prologue: stage kt=0 into buffer 0
    #pragma unroll
    for (int i = 0; i < 4; i++) {
        gload_lds16(xb + (size_t)srow[i] * 512 + schunk[i], (void*)&As[0][lds8[i]]);
        gload_lds16(vb + (size_t)srow[i] * 512 + schunk[i], (void*)&Bs[0][lds8[i]]);
    }
    __syncthreads();   // vmcnt(0) drain: buffer 0 ready

    for (int kt = 0; kt < 12; kt++) {
        int cur = kt & 1;
        if (kt < 11) {     // prefetch kt+1 into the other buffer; drained by end barrier
            int nk = kt + 1;
            int k4 = (nk & 3) * 64;
            int kcolA = (nk < 8) ? k4 : 256 + k4;
            int kcolB = (nk < 4) ? k4 : ((nk < 8) ? 256 + k4 : k4);
            #pragma unroll
            for (int i = 0; i < 4; i++) {
                gload_lds16(xb + (size_t)srow[i] * 512 + kcolA + schunk[i],
                            (void*)&As[1 - cur][lds8[i]]);
                gload_lds16(vb + (size_t)srow[i] * 512 + kcolB + schunk[i],
                            (void*)&Bs[1 - cur][lds8[i]]);
            }
        }
        #pragma unroll
        for (int ks = 0; ks < 2; ks++) {
            short8 af[4], bf[4];
            int ccr = ks * 4 + quad;
            #pragma unroll
            for (int f = 0; f < 4; f++) {
                int rA = wr * 64 + f * 16 + l16;
                af[f] = *(const short8*)&As[cur][(rA * 8 + (ccr ^ (rA & 7))) * 8];
                int rB = wc * 64 + f * 16 + l16;
                bf[f] = *(const short8*)&Bs[cur][(rB * 8 + (ccr ^ (rB & 7))) * 8];
            }
            #pragma unroll
            for (int fi = 0; fi < 4; fi++)
                #pragma unroll
                for (int fj = 0; fj < 4; fj++)
                    acc[fi][fj] = __builtin_amdgcn_mfma_f32_16x16x32_bf16(
                        af[fi], bf[fj], acc[fi][fj], 0, 0, 0);
        }
        __syncthreads();   // drains prefetch (next buffer ready) + all reads of cur done
    }

    // epilogue: per-row top-2 over this block's 128 centers (r6-validated verbatim)
    #pragma unroll
    for (int fi = 0; fi < 4; fi++) {
        #pragma unroll
        for (int r = 0; r < 4; r++) {
            int lrow = wr * 64 + fi * 16 + quad * 4 + r;
            float x2v = x2s[lrow];
            float bv1 = 3.4e38f, bv2 = 3.4e38f; int bi1 = 0x7fffffff, bi2 = 0x7fffffff;
            #pragma unroll
            for (int fj = 0; fj < 4; fj++) {
                int lcol = wc * 64 + fj * 16 + l16;
                float dist = fmaxf((x2v - 2.0f * acc[fi][fj][r]) + v2s[lcol], 0.0f);
                int cg = ch * 128 + lcol;
                if (dist < bv1 || (dist == bv1 && cg < bi1)) {
                    bv2 = bv1; bi2 = bi1; bv1 = dist; bi1 = cg;
                } else if (dist < bv2 || (dist == bv2 && cg < bi2)) {
                    bv2 = dist; bi2 = cg;
                }
            }
            #pragma unroll
            for (int off = 1; off < 16; off <<= 1) {
                float ov1 = __shfl_xor(bv1, off); int oi1 = __shfl_xor(bi1, off);
                float ov2 = __shfl_xor(bv2, off); int oi2 = __shfl_xor(bi2, off);
                if (ov1 < bv1 || (ov1 == bv1 && oi1 < bi1)) {
                    float nv2; int ni2;
                    if (bv1 < ov2 || (bv1 == ov2 && bi1 < oi2)) { nv2 = bv1; ni2 = bi1; }
                    else { nv2 = ov2; ni2 = oi2; }
                    bv1 = ov1; bi1 = oi1; bv2 = nv2; bi2 = ni2;
                } else if (ov1 < bv2 || (ov1 == bv2 && oi1 < bi2)) {
                    bv2 = ov1; bi2 = oi1;
                }
            }
            if (l16 == 0) {
                candv[lrow][wc][0] = bv1; candv[lrow][wc][1] = bv2;
                candi[lrow][wc][0] = bi1; candi[lrow][wc][1] = bi2;
            }
        }
    }
    __syncthreads();
    if (tid < 128) {
        float a1 = candv[tid][0][0], a2 = candv[tid][0][1];
        int   j1 = candi[tid][0][0], j2 = candi[tid][0][1];
        float o1 = candv[tid][1][0], o2 = candv[tid][1][1];
        int   p1 = candi[tid][1][0], p2 = candi[tid][1][1];
        float bv1, bv2; int bi1, bi2;
        if (o1 < a1 || (o1 == a1 && p1 < j1)) {
            bv1 = o1; bi1 = p1;
            if (a1 < o2 || (a1 == o2 && j1 < p2)) { bv2 = a1; bi2 = j1; }
            else { bv2 = o2; bi2 = p2; }
        } else {
            bv1 = a1; bi1 = j1;
            if (o1 < a2 || (o1 == a2 && p1 < j2)) { bv2 = o1; bi2 = p1; }
            else { bv2 = a2; bi2 = j2; }
        }
        size_t p = (size_t)(b * N + n0 + tid);
        pvals[p * 4 + ch] = make_float2(bv1, bv2);
        pinds[p * 4 + ch] = make_int2(bi1, bi2);
    }
}

// merge 4 chunk top-2s -> assign + cluster counts; flag points under rigorous error bound
__global__ void k_reduce2(const float2* __restrict__ pvals, const int2* __restrict__ pinds,
                          const float* __restrict__ x2, const float* __restrict__ xres,
                          const float* __restrict__ xlo,
                          const float* __restrict__ vmaxs, const float* __restrict__ vresmaxs,
                          const float* __restrict__ vlomaxs,
                          int* __restrict__ assign, int* __restrict__ counts,
                          int* __restrict__ refine_cnt, int* __restrict__ refine_pt) {
    int p = blockIdx.x * 256 + threadIdx.x;
    int b = p >> 14;
    float bv1 = 3.4e38f, bv2 = 3.4e38f; int bi1 = 0x7fffffff, bi2 = 0x7fffffff;
    #pragma unroll
    for (int ch = 0; ch < 4; ch++) {
        float2 vv = pvals[(size_t)p * 4 + ch];
        int2 ii = pinds[(size_t)p * 4 + ch];
        if (vv.x < bv1 || (vv.x == bv1 && ii.x < bi1)) {
            if (bv1 < vv.y || (bv1 == vv.y && bi1 < ii.y)) { bv2 = bv1; bi2 = bi1; }
            else { bv2 = vv.y; bi2 = ii.y; }
            bv1 = vv.x; bi1 = ii.x;
        } else if (vv.x < bv2 || (vv.x == bv2 && ii.x < bi2)) {
            bv2 = vv.x; bi2 = ii.x;
        }
    }
    assign[p] = bi1;
    atomicAdd(&counts[b * K + bi1], 1);
    // |dot err| <= xres*||v||max + ||x||*vresmax + xlo*vlomax (dropped xl*vl) [+ MFMA ~4e-4]
    float thr = 4.0f * (xres[p] * vmaxs[b] + sqrtf(x2[p]) * vresmaxs[b]
                        + xlo[p] * vlomaxs[b]) + 4e-3f;
    if (bv2 - bv1 < thr) {
        int pos = atomicAdd(refine_cnt, 1);
        refine_pt[pos] = p;
    }
}

// exact fp32 rescan over ALL 512 centers for flagged points; fixes counts on change
__global__ __launch_bounds__(256) void k_rescan(
    const float* __restrict__ x, const float* __restrict__ vT,
    const float* __restrict__ x2, const float* __restrict__ v2,
    const int* __restrict__ refine_cnt, const int* __restrict__ refine_pt,
    int* __restrict__ assign, int* __restrict__ counts) {
    __shared__ float xs[256];
    __shared__ float rv[256];
    __shared__ int ri[256];
    int cnt = *refine_cnt;
    int t = threadIdx.x;
    for (int i = blockIdx.x; i < cnt; i += gridDim.x) {
        int p = refine_pt[i];
        int b = p >> 14;
        xs[t] = x[(size_t)p * D + t];
        __syncthreads();
        const float* vtb = vT + (size_t)b * D * K;
        float s0 = 0.f, s1 = 0.f;
        for (int d = 0; d < D; d++) {
            float xd = xs[d];
            s0 = fmaf(xd, vtb[(size_t)d * K + t], s0);
            s1 = fmaf(xd, vtb[(size_t)d * K + 256 + t], s1);
        }
        float x2p = x2[p];
        float d0 = fmaxf((x2p - 2.0f * s0) + v2[b * K + t], 0.0f);
        float d1 = fmaxf((x2p - 2.0f * s1) + v2[b * K + 256 + t], 0.0f);
        float bv; int bi;
        if (d1 < d0) { bv = d1; bi = t + 256; } else { bv = d0; bi = t; }
        rv[t] = bv; ri[t] = bi;
        __syncthreads();
        for (int s = 128; s; s >>= 1) {
            if (t < s) {
                if (rv[t + s] < rv[t] || (rv[t + s] == rv[t] && ri[t + s] < ri[t])) {
                    rv[t] = rv[t + s]; ri[t] = ri[t + s];
                }
            }
            __syncthreads();
        }
        if (t == 0) {
            int old = assign[p];
            int neu = ri[0];
            if (neu != old) {
                assign[p] = neu;
                atomicSub(&counts[b * K + old], 1);
                atomicAdd(&counts[b * K + neu], 1);
            }
        }
        __syncthreads();
    }
}

// =================== membership -> new centers (proven) ===================

__global__ __launch_bounds__(256) void k_scatter(
    const int* __restrict__ assign, const int* __restrict__ counts,
    int* __restrict__ cursor, int* __restrict__ order) {
    __shared__ int offs[K];
    int b = blockIdx.y;
    if (threadIdx.x < 64) {
        int lane = threadIdx.x;
        int pre[8]; int s = 0;
        #pragma unroll
        for (int j = 0; j < 8; j++) { pre[j] = s; s += counts[b * K + lane * 8 + j]; }
        int inc = s;
        #pragma unroll
        for (int off = 1; off < 64; off <<= 1) {
            int o = __shfl_up(inc, off);
            if (lane >= off) inc += o;
        }
        int excl = inc - s;
        #pragma unroll
        for (int j = 0; j < 8; j++) offs[lane * 8 + j] = excl + pre[j];
    }
    __syncthreads();
    int n = blockIdx.x * 256 + threadIdx.x;
    int a = assign[b * N + n];
    int pos = atomicAdd(&cursor[b * K + a], 1);
    order[b * N + offs[a] + pos] = n;
}

__global__ __launch_bounds__(256) void k_sumdiv(
    const float* __restrict__ x, const int* __restrict__ counts,
    const int* __restrict__ order, const float* __restrict__ totsum,
    float* __restrict__ v) {
    __shared__ int sh[256];
    __shared__ int ord[256];
    int t = threadIdx.x;
    int b = blockIdx.y, k = blockIdx.x;
    const int* cb = counts + b * K;
    int partial = 0;
    for (int j = t; j < k; j += 256) partial += cb[j];
    sh[t] = partial; __syncthreads();
    for (int s = 128; s; s >>= 1) { if (t < s) sh[t] += sh[t + s]; __syncthreads(); }
    int off = sh[0];
    int cnt = cb[k];
    const float* xb = x + (size_t)b * N * D;
    float acc = 0.f;
    for (int m0 = 0; m0 < cnt; m0 += 256) {
        int mm = min(256, cnt - m0);
        if (t < mm) ord[t] = order[b * N + off + m0 + t];
        __syncthreads();
        for (int m = 0; m < mm; m++) {
            int n = ord[m];
            acc += xb[(size_t)n * D + t];
        }
        __syncthreads();
    }
    float out;
    if (cnt > 0) out = acc * (1.0f / (float)cnt);
    else out = totsum[b * D + t];
    v[((size_t)b * K + k) * D + t] = out;
}

__global__ void k_write_u(const int* __restrict__ assign, float* __restrict__ uout) {
    int idx = blockIdx.x * 256 + threadIdx.x;
    int a = assign[idx];
    uout[(size_t)idx * K + a] = 1.0f;
}

__global__ void k_copy_v(const float* __restrict__ v, float* __restrict__ out) {
    int idx = blockIdx.x * 256 + threadIdx.x;
    ((float4*)out)[idx] = ((const float4*)v)[idx];
}

extern "C" void kernel_launch(void* const* d_in, const int* in_sizes, int n_in,
                              void* d_out, int out_size, void* d_ws, size_t ws_size,
                              hipStream_t stream) {
    const float* x = (const float*)d_in[0];
    float* out = (float*)d_out;
    char* ws = (char*)d_ws;

    // ---- ws: proven-small footprint (<3.0 MB) ----
    size_t off = 0;
    float* v      = (float*)(ws + off); off += (size_t)B * K * D * 4;
    float* x2     = (float*)(ws + off); off += (size_t)B * N * 4;
    float* v2     = (float*)(ws + off); off += (size_t)B * K * 4;
    float* totsum = (float*)(ws + off); off += (size_t)B * D * 4;
    int* assign   = (int*)(ws + off);   off += (size_t)B * N * 4;
    int* counts   = (int*)(ws + off);   off += (size_t)B * K * 4;   // counts+cursor contiguous
    int* cursor   = (int*)(ws + off);   off += (size_t)B * K * 4;
    int* order    = (int*)(ws + off);   off += (size_t)B * N * 4;
    int* inds     = (int*)(ws + off);   off += 4096;
    int* refine_cnt = (int*)(ws + off); off += 256;

    // ---- big scratch in d_out u-region (134 MB; r4/r6-r9-proven home) ----
    char* ob = (char*)out;
    size_t oboff = 0;
    unsigned short* xcat = (unsigned short*)(ob + oboff); oboff += (size_t)B * N * 512 * 2;  // 64 MiB
    float2* pvals  = (float2*)(ob + oboff); oboff += (size_t)B * N * 4 * sizeof(float2);     // 2 MiB
    int2* pinds    = (int2*)(ob + oboff);   oboff += (size_t)B * N * 4 * sizeof(int2);       // 2 MiB
    int* refine_pt = (int*)(ob + oboff);    oboff += (size_t)B * N * 4;                      // 256 KiB
    float* vT      = (float*)(ob + oboff);  oboff += (size_t)B * K * D * 4;                  // 2 MiB
    float* xres    = (float*)(ob + oboff);  oboff += (size_t)B * N * 4;                      // 256 KiB
    float* xlo     = (float*)(ob + oboff);  oboff += (size_t)B * N * 4;                      // 256 KiB
    float* vres    = (float*)(ob + oboff);  oboff += (size_t)B * K * 4;                      // 8 KiB
    float* vlo     = (float*)(ob + oboff);  oboff += (size_t)B * K * 4;                      // 8 KiB
    float* vmaxs   = (float*)(ob + oboff);  oboff += 256;
    float* vresmaxs = (float*)(ob + oboff); oboff += 256;
    float* vlomaxs = (float*)(ob + oboff);  oboff += 256;
    unsigned short* vcat = (unsigned short*)(out + (size_t)B * N * K);  // v-region, 2 MiB exact

    static int h_inds[K];
    host_sample_inds(h_inds);
    hipMemcpyAsync(inds, h_inds, K * sizeof(int), hipMemcpyHostToDevice, stream);

    hipMemsetAsync(totsum, 0, (size_t)B * D * 4, stream);
    k_gather_v0<<<B * K, 64, 0, stream>>>(x, inds, v);
    k_totsum<<<dim3(64, B), 256, 0, stream>>>(x, totsum);
    k_prep<<<(B * N) / 4, 256, 0, stream>>>(x, xcat, x2, xres, xlo);

    for (int it = 0; it < ITERS; it++) {
        k_prep<<<(B * K) / 4, 256, 0, stream>>>(v, vcat, v2, vres, vlo);
        k_errmax<<<B, 256, 0, stream>>>(v2, vres, vlo, vmaxs, vresmaxs, vlomaxs);
        k_transpose<<<(B * K * D) / 256, 256, 0, stream>>>(v, vT);
        k_gemm_assign<<<dim3(K / 128, N / 128, B), 256, 0, stream>>>(
            xcat, vcat, x2, v2, pvals, pinds);
        hipMemsetAsync(refine_cnt, 0, 256, stream);
        hipMemsetAsync(counts, 0, 2 * (size_t)B * K * 4, stream);  // counts + cursor
        k_reduce2<<<(B * N) / 256, 256, 0, stream>>>(pvals, pinds, x2, xres, xlo,
                                                     vmaxs, vresmaxs, vlomaxs,
                                                     assign, counts, refine_cnt, refine_pt);
        k_rescan<<<1024, 256, 0, stream>>>(x, vT, x2, v2, refine_cnt, refine_pt,
                                           assign, counts);
        k_scatter<<<dim3(N / 256, B), 256, 0, stream>>>(assign, counts, cursor, order);
        k_sumdiv<<<dim3(K, B), 256, 0, stream>>>(x, counts, order, totsum, v);
    }

    hipMemsetAsync(out, 0, (size_t)B * N * K * 4, stream);
    k_write_u<<<(B * N) / 256, 256, 0, stream>>>(assign, out);
    k_copy_v<<<(B * K * D) / 1024, 256, 0, stream>>>(v, out + (size_t)B * N * K);
}